// Round 1
// baseline (3467.492 us; speedup 1.0000x reference)
//
#include <hip/hip_runtime.h>
#include <hip/hip_bf16.h>
#include <math.h>

// Problem constants
#define BQ    8
#define E     256
#define HW    1024               // 32*32
#define NTOK  8192               // BQ*HW
#define NE    16384
#define NSPLIT 8
#define CODES_PER_BLK (NE / NSPLIT)   // 2048
#define GBATCH 16

// ---------------------------------------------------------------------------
// Kernel 1: cnorm[n] = sum_k codebook[n][k]^2   (wave per row, float4 loads)
// ---------------------------------------------------------------------------
__global__ __launch_bounds__(256) void k_cnorm(const float* __restrict__ cb,
                                               float* __restrict__ cnorm) {
    const int wid  = threadIdx.x >> 6;
    const int lane = threadIdx.x & 63;
    const int row  = blockIdx.x * 4 + wid;
    const float4* r = (const float4*)(cb + (size_t)row * E);
    float4 v = r[lane];
    float s = v.x * v.x + v.y * v.y + v.z * v.z + v.w * v.w;
#pragma unroll
    for (int off = 32; off >= 1; off >>= 1) s += __shfl_xor(s, off, 64);
    if (lane == 0) cnorm[row] = s;
}

// ---------------------------------------------------------------------------
// Kernel 2: fused distance + running argmin over a code range.
// lane = token (64 tokens/block), wave w owns K-part [w*64, w*64+64) held in
// VGPRs; codebook values come in via scalar loads (wave-uniform address) so
// the inner loop is pure v_fma_f32 with an SGPR operand -> ~zero LDS traffic.
// Partial dots for 16 codes are summed across the 4 waves through a
// double-buffered LDS tile with ONE barrier per 16 codes.
// ---------------------------------------------------------------------------
__global__ __launch_bounds__(256, 4) void k_argmin(
    const float* __restrict__ z, const float* __restrict__ cb,
    const float* __restrict__ cnorm,
    float* __restrict__ pmin, int* __restrict__ pidx)
{
    __shared__ float lds[8192];                 // 32 KB: two 4096-float buffers
    const int tid  = threadIdx.x;
    const int lane = tid & 63;
    const int wid  = __builtin_amdgcn_readfirstlane(tid >> 6); // force SGPR
    const int tile = blockIdx.x;                // 0..127  (token tile)
    const int ns   = blockIdx.y;                // 0..7    (code split)
    const int b    = tile >> 4;
    const int hw0  = (tile & 15) << 6;

    // ---- stage x into registers: xr[k] = z[b][wid*64+k][hw0+lane] ----------
    float xr[64];
    for (int kc = 0; kc < 4; ++kc) {
#pragma unroll
        for (int i = 0; i < 16; ++i) {
            int linear = tid + 256 * i;         // 0..4095 ; r=linear>>6, c=&63
            int r = linear >> 6, c = linear & 63;
            lds[linear] = z[(size_t)b * (E * HW) + (size_t)(kc * 64 + r) * HW + hw0 + c];
        }
        __syncthreads();
        if (wid == kc) {
#pragma unroll
            for (int k = 0; k < 64; ++k) xr[k] = lds[k * 64 + lane];
        }
        __syncthreads();
    }

    float bmin = INFINITY;
    int   bidx = 0x7fffffff;
    const int n0 = ns * CODES_PER_BLK;
    const float* __restrict__ cbw = cb + (size_t)wid * 64;

    for (int batch = 0; batch < CODES_PER_BLK / GBATCH; ++batch) {
        float* buf = lds + (batch & 1) * 4096;
        const int nb = n0 + batch * GBATCH;

        // compute phase: partial dot over this wave's K-part, 16 codes
#pragma unroll 1
        for (int g = 0; g < GBATCH; ++g) {
            const float* __restrict__ cp = cbw + (size_t)(nb + g) * E;  // uniform -> s_load
            float a0 = 0.f, a1 = 0.f, a2 = 0.f, a3 = 0.f;
#pragma unroll
            for (int k = 0; k < 64; k += 4) {
                a0 = fmaf(xr[k],     cp[k],     a0);
                a1 = fmaf(xr[k + 1], cp[k + 1], a1);
                a2 = fmaf(xr[k + 2], cp[k + 2], a2);
                a3 = fmaf(xr[k + 3], cp[k + 3], a3);
            }
            buf[wid * 1024 + g * 64 + lane] = (a0 + a1) + (a2 + a3);
        }
        __syncthreads();

        // reduce phase: wave `wid` handles codes g in [wid*4, wid*4+4)
#pragma unroll
        for (int i = 0; i < 4; ++i) {
            int g = wid * 4 + i;
            float v = buf[g * 64 + lane] + buf[1024 + g * 64 + lane]
                    + buf[2048 + g * 64 + lane] + buf[3072 + g * 64 + lane];
            float d = cnorm[nb + g] - 2.0f * v;   // |x|^2 dropped (argmin-invariant)
            int   n = nb + g;
            if (d < bmin) { bmin = d; bidx = n; } // ascending n -> keeps first min
        }
        // no barrier needed: double-buffered; next batch's barrier orders reuse
    }

    // ---- cross-wave (4 groups per token) final reduce ----------------------
    __syncthreads();
    lds[wid * 64 + lane] = bmin;
    ((int*)lds)[256 + wid * 64 + lane] = bidx;
    __syncthreads();
    if (tid < 64) {
        float m = lds[tid]; int mi = ((int*)lds)[256 + tid];
#pragma unroll
        for (int w = 1; w < 4; ++w) {
            float v = lds[w * 64 + tid]; int vi = ((int*)lds)[256 + w * 64 + tid];
            if (v < m || (v == m && vi < mi)) { m = v; mi = vi; }
        }
        int t = tile * 64 + tid;                // == b*1024 + hw0 + tid
        pmin[ns * NTOK + t] = m;
        pidx[ns * NTOK + t] = mi;
    }
}

// ---------------------------------------------------------------------------
// Kernel 3: reduce the NSPLIT partial (min,idx) pairs per token
// ---------------------------------------------------------------------------
__global__ __launch_bounds__(256) void k_pick(const float* __restrict__ pmin,
                                              const int* __restrict__ pidx,
                                              int* __restrict__ idxf) {
    int t = blockIdx.x * 256 + threadIdx.x;     // 0..8191
    float m = pmin[t]; int mi = pidx[t];
#pragma unroll
    for (int s = 1; s < NSPLIT; ++s) {
        float v = pmin[(size_t)s * NTOK + t]; int vi = pidx[(size_t)s * NTOK + t];
        if (v < m || (v == m && vi < mi)) { m = v; mi = vi; }
    }
    idxf[t] = mi;
}

// ---------------------------------------------------------------------------
// Kernel 4: gather codebook rows -> out[B,E,H,W], LDS transpose (pad 257).
// Both global sides coalesced; LDS reads/writes conflict-free.
// out = x + (x_q - x), mimicking the reference's straight-through arithmetic.
// ---------------------------------------------------------------------------
__global__ __launch_bounds__(256) void k_out(const float* __restrict__ z,
                                             const float* __restrict__ cb,
                                             const int* __restrict__ idxf,
                                             float* __restrict__ out) {
    __shared__ float xq[32 * 257];
    const int tid  = threadIdx.x;
    const int tile = blockIdx.x;                // 0..255
    const int b    = tile >> 5;
    const int hw0  = (tile & 31) << 5;          // 32 tokens per block
#pragma unroll
    for (int r = 0; r < 32; ++r) {
        int code = idxf[b * HW + hw0 + r];      // uniform -> s_load
        xq[r * 257 + tid] = cb[(size_t)code * E + tid];   // coalesced over e
    }
    __syncthreads();
    const int grp = tid >> 5, l = tid & 31;     // l = token row, grp = e-octant
#pragma unroll
    for (int j = 0; j < 32; ++j) {
        int e = grp * 32 + j;
        size_t o = (size_t)b * (E * HW) + (size_t)e * HW + hw0 + l;
        float x = z[o];
        out[o] = x + (xq[l * 257 + e] - x);
    }
}

// ---------------------------------------------------------------------------
extern "C" void kernel_launch(void* const* d_in, const int* in_sizes, int n_in,
                              void* d_out, int out_size, void* d_ws, size_t ws_size,
                              hipStream_t stream) {
    const float* z  = (const float*)d_in[0];    // [8,256,32,32]
    const float* cb = (const float*)d_in[1];    // [16384,256]
    float* out = (float*)d_out;

    float* ws    = (float*)d_ws;
    float* cnorm = ws;                                   // 16384 f
    float* pmin  = ws + NE;                              // NSPLIT*NTOK f
    int*   pidx  = (int*)(ws + NE + NSPLIT * NTOK);      // NSPLIT*NTOK i
    int*   idxf  = (int*)(ws + NE + 2 * NSPLIT * NTOK);  // NTOK i
    // total ws: (16384 + 65536 + 65536 + 8192)*4 B ~= 608 KB

    k_cnorm <<<NE / 4, 256, 0, stream>>>(cb, cnorm);
    k_argmin<<<dim3(NTOK / 64, NSPLIT), 256, 0, stream>>>(z, cb, cnorm, pmin, pidx);
    k_pick  <<<NTOK / 256, 256, 0, stream>>>(pmin, pidx, idxf);
    k_out   <<<NTOK / 32, 256, 0, stream>>>(z, cb, idxf, out);
}